// Round 5
// baseline (202.902 us; speedup 1.0000x reference)
//
#include <hip/hip_runtime.h>
#include <hip/hip_bf16.h>
#include <cstdint>
#include <cstddef>

#define EPS 1e-8f

typedef __attribute__((ext_vector_type(8))) short short8;
typedef __attribute__((ext_vector_type(4))) float floatx4;

static constexpr int Bb = 16, Nn = 1024, Dd = 256, Kk = 256;
static constexpr int M = Bb * Nn;                      // 16384
static constexpr size_t PM = (size_t)M * 256;          // 4,194,304 elements per modality plane

// d_out element offsets (f32)
static constexpr size_t OUT_Z      = 0;
static constexpr size_t OUT_ASSIGN = 2 * PM;
static constexpr size_t OUT_SIM    = 4 * PM;
static constexpr size_t OUT_SEM    = 6 * PM;

// ws byte offsets
static constexpr size_t OFF_QB  = 16777216;            // q0 bf16 2*PM
static constexpr size_t OFF_PN  = 33554432;            // pn bf16 2*64K
static constexpr size_t OFF_PNT = 33816576;            // pnt bf16
static constexpr size_t OFF_U   = 34078720;            // u f32 2*M
static constexpr size_t OFF_T   = 34209792;            // Tg 32 f32
static constexpr size_t OFF_SC  = 34209920;            // Sc 2*6*16*256 f32
static constexpr size_t OFF_CS  = 34406528;            // cs 2*16*256 f32
static constexpr size_t ZERO_OFF = OFF_T;
static constexpr size_t ZERO_SZ  = 128 + 196608 + 32768;
static constexpr int    NZ_FLOATS = (int)(ZERO_SZ / 4);

__device__ __forceinline__ unsigned short f2bf(float f) {
    unsigned int b = __float_as_uint(f);
    b += 0x7fffu + ((b >> 16) & 1u);          // RNE
    return (unsigned short)(b >> 16);
}
__device__ __forceinline__ float bf2f(unsigned short u) {
    return __uint_as_float(((unsigned int)u) << 16);
}

typedef const __attribute__((address_space(1))) unsigned int* gas_u32p;
typedef __attribute__((address_space(3))) unsigned int* las_u32p;
__device__ __forceinline__ void lds_cp16(const unsigned short* g, short* l) {
    __builtin_amdgcn_global_load_lds((gas_u32p)g, (las_u32p)l, 16, 0, 0);
}

// ---------------- proto normalize (+ fused scratch zeroing) ----------------
__global__ __launch_bounds__(64) void proto_kernel(const float* __restrict__ pr,
                                                   const float* __restrict__ ps,
                                                   unsigned short* __restrict__ pn,
                                                   unsigned short* __restrict__ pnt,
                                                   float* __restrict__ zp) {
    int gid = blockIdx.x * 64 + threadIdx.x;           // 0..32767
    for (int i = gid; i < NZ_FLOATS; i += 32768) zp[i] = 0.f;

    int row = blockIdx.x & 255;
    int mod = blockIdx.x >> 8;
    const float* p = (mod ? ps : pr) + (size_t)row * 256;
    int lane = threadIdx.x;
    float4 v = ((const float4*)p)[lane];
    float ss = v.x * v.x + v.y * v.y + v.z * v.z + v.w * v.w;
    #pragma unroll
    for (int m = 1; m < 64; m <<= 1) ss += __shfl_xor(ss, m);
    float sc = 1.0f / (sqrtf(ss) + EPS);
    ushort4 u4;
    u4.x = f2bf(v.x * sc); u4.y = f2bf(v.y * sc);
    u4.z = f2bf(v.z * sc); u4.w = f2bf(v.w * sc);
    *(ushort4*)(pn + (size_t)mod * 65536 + (size_t)row * 256 + lane * 4) = u4;
    unsigned short* pt = pnt + (size_t)mod * 65536 + row;
    pt[(size_t)(lane * 4 + 0) * 256] = u4.x;
    pt[(size_t)(lane * 4 + 1) * 256] = u4.y;
    pt[(size_t)(lane * 4 + 2) * 256] = u4.z;
    pt[(size_t)(lane * 4 + 3) * 256] = u4.w;
}

// ---------------- GEMM0 fused with prep: normalize f rows -> A resident in LDS ----------------
// (verified round-4 kernel, unchanged)
__global__ __launch_bounds__(256) void gemm0_fused(const float* __restrict__ fr,
                                                   const float* __restrict__ fs,
                                                   const unsigned short* __restrict__ pn,
                                                   unsigned short* __restrict__ qb,
                                                   float* __restrict__ doutf,
                                                   float* __restrict__ Tg) {
    __shared__ __align__(16) char smem[81920];
    short* Afull = (short*)smem;             // 65536 B
    short* Bl    = (short*)(smem + 65536);   // 16384 B (per-kh)

    int bx = blockIdx.x, by = blockIdx.y, mod = blockIdx.z;
    int t = threadIdx.x, lane = t & 63, wv = t >> 6;
    int wrow = (wv >> 1) * 64, wcol = (wv & 1) * 64;
    int g = lane >> 4, ml = lane & 15;

    const float* F0 = (mod ? fs : fr) + (size_t)by * 128 * 256;
    const unsigned short* B0 = pn + (size_t)mod * 65536 + (size_t)bx * 128 * 256;

    // ---- build A: normalize rows (identical 64-lane butterfly as old prep) ----
    for (int bs = 0; bs < 4; bs++) {
        int rbase = wv * 32 + bs * 8;
        float4 vv[8];
        #pragma unroll
        for (int i = 0; i < 8; i++)
            vv[i] = ((const float4*)(F0 + (size_t)(rbase + i) * 256))[lane];
        #pragma unroll
        for (int i = 0; i < 8; i++) {
            float ss = vv[i].x * vv[i].x + vv[i].y * vv[i].y
                     + vv[i].z * vv[i].z + vv[i].w * vv[i].w;
            #pragma unroll
            for (int m = 1; m < 64; m <<= 1) ss += __shfl_xor(ss, m);
            float sc = 1.0f / (sqrtf(ss) + EPS);
            ushort4 u4;
            u4.x = f2bf(vv[i].x * sc); u4.y = f2bf(vv[i].y * sc);
            u4.z = f2bf(vv[i].z * sc); u4.w = f2bf(vv[i].w * sc);
            int row = rbase + i;
            int off = row * 256 + (((lane >> 1) ^ (row & 7)) << 3) + ((lane & 1) << 2);
            *(ushort4*)&Afull[off] = u4;
        }
    }

    floatx4 acc[4][4];
    #pragma unroll
    for (int i = 0; i < 4; i++)
        #pragma unroll
        for (int j = 0; j < 4; j++) acc[i][j] = (floatx4){0.f, 0.f, 0.f, 0.f};

    for (int kh = 0; kh < 4; kh++) {
        #pragma unroll
        for (int i = 0; i < 4; i++) {
            int sI = i * 256 + t;
            int r = sI >> 3, cs = sI & 7;
            int cg = cs ^ (r & 7);
            size_t goff = (size_t)r * 256 + kh * 64 + cg * 8;
            lds_cp16(B0 + goff, &Bl[sI * 8]);
        }
        __syncthreads();                      // kh=0: also publishes A build
        #pragma unroll
        for (int ks = 0; ks < 2; ks++) {
            short8 af[4], bfr[4];
            int c = ks * 4 + g;
            int c8 = kh * 8 + c;
            #pragma unroll
            for (int mt = 0; mt < 4; mt++) {
                int row = wrow + mt * 16 + ml;
                af[mt] = *(const short8*)&Afull[row * 256 + ((c8 ^ (row & 7)) << 3)];
            }
            #pragma unroll
            for (int nt = 0; nt < 4; nt++) {
                int col = wcol + nt * 16 + ml;
                bfr[nt] = *(const short8*)&Bl[col * 64 + ((c ^ (col & 7)) << 3)];
            }
            #pragma unroll
            for (int mt = 0; mt < 4; mt++)
                #pragma unroll
                for (int nt = 0; nt < 4; nt++)
                    acc[mt][nt] = __builtin_amdgcn_mfma_f32_16x16x32_bf16(af[mt], bfr[nt], acc[mt][nt], 0, 0, 0);
        }
        __syncthreads();
    }

    int g4 = g << 2;
    float tsum = 0.f;
    #pragma unroll
    for (int mt = 0; mt < 4; mt++)
        #pragma unroll
        for (int nt = 0; nt < 4; nt++)
            #pragma unroll
            for (int reg = 0; reg < 4; reg++) {
                float s = acc[mt][nt][reg];
                int row = by * 128 + wrow + mt * 16 + g4 + reg;
                int col = bx * 128 + wcol + nt * 16 + ml;
                size_t idx = (size_t)row * 256 + col;
                doutf[OUT_SIM + (size_t)mod * PM + idx] = s;
                unsigned short eb = f2bf(__expf(s * 20.0f));   // exp(sim/tau), tau=0.05
                qb[(size_t)mod * PM + idx] = eb;
                tsum += bf2f(eb);
            }
    #pragma unroll
    for (int mk = 1; mk < 64; mk <<= 1) tsum += __shfl_xor(tsum, mk);
    float* tred = (float*)(smem + 65536);     // Bl dead after last sync
    if (lane == 0) tred[wv] = tsum;
    __syncthreads();
    if (t == 0) atomicAdd(&Tg[mod * 16 + (by >> 3)], tred[0] + tred[1] + tred[2] + tred[3]);
}

// ---------------- Sinkhorn passes 1..5: SINGLE q sweep per pass ----------------
// Thread (wv,lane) owns rows wv*8+k (k<8) at cols lane*4..+3 — q loaded once into regs.
// Row sums via 64-lane shfl_xor butterfly on 4-col partials (all lanes get identical
// full sum -> un computed redundantly, bit-identical). Col partials reuse the same regs.
__global__ __launch_bounds__(256) void pass_kernel(const unsigned short* __restrict__ qbg,
                                                   float* __restrict__ u,
                                                   const float* __restrict__ Tg,
                                                   float* __restrict__ Sc,
                                                   int pass) {
    __shared__ float vcur[256];
    __shared__ float wsum[4][256];
    int tile = blockIdx.x, b = blockIdx.y, mod = blockIdx.z;
    int t = threadIdx.x;
    {
        float v = 1.0f;
        for (int j = 1; j < pass; j++) {
            float sc = Sc[((size_t)(mod * 6 + j) * 16 + b) * 256 + t];
            v = v * (1.0f / 256.0f) / (v * sc + EPS);
        }
        vcur[t] = v;
    }
    __syncthreads();

    int wv = t >> 6, lane = t & 63;
    float4 vv = *(const float4*)(vcur + lane * 4);
    size_t rowbase = (size_t)b * 1024 + tile * 32;               // global row base
    const unsigned short* qbase = qbg + ((size_t)mod * M + rowbase) * 256;
    float* ub = u + (size_t)mod * M + rowbase;
    float u0 = (pass == 1) ? 1.0f / (Tg[mod * 16 + b] + EPS) : 0.f;

    float c0 = 0.f, c1 = 0.f, c2 = 0.f, c3 = 0.f;
    #pragma unroll
    for (int k = 0; k < 8; k++) {
        int rr = wv * 8 + k;
        ushort4 qv = *(const ushort4*)(qbase + (size_t)rr * 256 + lane * 4);
        float q0 = bf2f(qv.x), q1 = bf2f(qv.y), q2 = bf2f(qv.z), q3 = bf2f(qv.w);
        float pr = q0 * vv.x + q1 * vv.y + q2 * vv.z + q3 * vv.w;
        #pragma unroll
        for (int m = 1; m < 64; m <<= 1) pr += __shfl_xor(pr, m);
        float up = (pass == 1) ? u0 : ub[rr];                    // uniform addr per wave
        float un = up * (1.0f / 1024.0f) / (up * pr + EPS);
        if (lane == k) ub[rr] = un;
        c0 += q0 * un; c1 += q1 * un; c2 += q2 * un; c3 += q3 * un;
    }
    *(float4*)&wsum[wv][lane * 4] = make_float4(c0, c1, c2, c3);
    __syncthreads();
    {
        float ssum = wsum[0][t] + wsum[1][t] + wsum[2][t] + wsum[3][t];
        atomicAdd(&Sc[((size_t)(mod * 6 + pass) * 16 + b) * 256 + t], ssum);
    }
}

// ---------------- GEMM1 fused with pass 6: single q sweep builds assign -> z ----------------
// Phase 0: v6 chain from Sc[1..5]. Phase 1+2 merged: per 32-row group, q in regs;
// butterfly row sums -> un; a = q*un*v -> assign f32 (bx==0), bf16 swizzled Afull,
// cs partials. Phase 3: MFMA vs pnt (per-kh staged). LDS 80 KB -> 2 blocks/CU.
__global__ __launch_bounds__(256) void gemm1_fused(const unsigned short* __restrict__ qbg,
                                                   const unsigned short* __restrict__ pnt,
                                                   const float* __restrict__ u,
                                                   const float* __restrict__ Sc,
                                                   float* __restrict__ cs,
                                                   float* __restrict__ doutf) {
    __shared__ __align__(16) char smem[81920];
    short* Afull = (short*)smem;                     // 65536 B
    short* Bl    = (short*)(smem + 65536);           // 16384 B (phase 3)
    float* vl    = (float*)(smem + 65536);           // overlay: 256 f32 (build)
    float* wsum  = (float*)(smem + 65536 + 2048);    // overlay: 4*256 f32

    int bx = blockIdx.x, by = blockIdx.y, mod = blockIdx.z;
    int b = by >> 3;
    int t = threadIdx.x, lane = t & 63, wv = t >> 6;
    int wrow = (wv >> 1) * 64, wcol = (wv & 1) * 64;
    int g = lane >> 4, ml = lane & 15;
    size_t rowg0 = (size_t)by * 128;

    // ---- phase 0: v6 chain ----
    {
        float v = 1.0f;
        #pragma unroll
        for (int j = 1; j <= 5; j++) {
            float scv = Sc[((size_t)(mod * 6 + j) * 16 + b) * 256 + t];
            v = v * (1.0f / 256.0f) / (v * scv + EPS);
        }
        vl[t] = v;
    }
    __syncthreads();

    // ---- phase 1+2 merged: single q sweep ----
    {
        float4 vv = *(const float4*)(vl + lane * 4);
        float* aout = doutf + OUT_ASSIGN + (size_t)mod * PM;
        const float* ug = u + (size_t)mod * M + rowg0;
        float c0 = 0.f, c1 = 0.f, c2 = 0.f, c3 = 0.f;
        for (int s = 0; s < 4; s++) {
            #pragma unroll
            for (int k = 0; k < 8; k++) {
                int rl = s * 32 + wv * 8 + k;
                size_t rowg = rowg0 + rl;
                ushort4 qv = *(const ushort4*)(qbg + ((size_t)mod * PM + rowg * 256) + lane * 4);
                float q0 = bf2f(qv.x), q1 = bf2f(qv.y), q2 = bf2f(qv.z), q3 = bf2f(qv.w);
                float pr = q0 * vv.x + q1 * vv.y + q2 * vv.z + q3 * vv.w;
                #pragma unroll
                for (int m = 1; m < 64; m <<= 1) pr += __shfl_xor(pr, m);
                float up = ug[rl];                    // uniform addr per wave
                float un = up / (up * pr + EPS);      // pass-6 formula
                float a0 = q0 * un * vv.x, a1 = q1 * un * vv.y;
                float a2 = q2 * un * vv.z, a3 = q3 * un * vv.w;
                if (bx == 0) *(float4*)(aout + rowg * 256 + lane * 4) = make_float4(a0, a1, a2, a3);
                ushort4 o;
                o.x = f2bf(a0); o.y = f2bf(a1); o.z = f2bf(a2); o.w = f2bf(a3);
                int off = rl * 256 + (((lane >> 1) ^ (rl & 7)) << 3) + ((lane & 1) << 2);
                *(ushort4*)&Afull[off] = o;
                c0 += a0; c1 += a1; c2 += a2; c3 += a3;
            }
        }
        *(float4*)&wsum[wv * 256 + lane * 4] = make_float4(c0, c1, c2, c3);
    }
    __syncthreads();
    if (bx == 0) {
        float ssum = wsum[0 * 256 + t] + wsum[1 * 256 + t] + wsum[2 * 256 + t] + wsum[3 * 256 + t];
        atomicAdd(&cs[((size_t)mod * 16 + b) * 256 + t], ssum);
    }
    __syncthreads();                                   // wsum/vl reads done before Bl staging

    // ---- phase 3: MFMA vs pnt ----
    const unsigned short* B0 = pnt + (size_t)mod * 65536 + (size_t)bx * 128 * 256;
    floatx4 acc[4][4];
    #pragma unroll
    for (int i = 0; i < 4; i++)
        #pragma unroll
        for (int j = 0; j < 4; j++) acc[i][j] = (floatx4){0.f, 0.f, 0.f, 0.f};

    for (int kh = 0; kh < 4; kh++) {
        #pragma unroll
        for (int i = 0; i < 4; i++) {
            int sI = i * 256 + t;
            int rr = sI >> 3, cc = sI & 7;
            int cg = cc ^ (rr & 7);
            size_t goff = (size_t)rr * 256 + kh * 64 + cg * 8;
            lds_cp16(B0 + goff, &Bl[sI * 8]);
        }
        __syncthreads();
        #pragma unroll
        for (int ks = 0; ks < 2; ks++) {
            short8 af[4], bfr[4];
            int c = ks * 4 + g;
            int c8 = kh * 8 + c;
            #pragma unroll
            for (int mt = 0; mt < 4; mt++) {
                int row = wrow + mt * 16 + ml;
                af[mt] = *(const short8*)&Afull[row * 256 + ((c8 ^ (row & 7)) << 3)];
            }
            #pragma unroll
            for (int nt = 0; nt < 4; nt++) {
                int col = wcol + nt * 16 + ml;
                bfr[nt] = *(const short8*)&Bl[col * 64 + ((c ^ (col & 7)) << 3)];
            }
            #pragma unroll
            for (int mt = 0; mt < 4; mt++)
                #pragma unroll
                for (int nt = 0; nt < 4; nt++)
                    acc[mt][nt] = __builtin_amdgcn_mfma_f32_16x16x32_bf16(af[mt], bfr[nt], acc[mt][nt], 0, 0, 0);
        }
        __syncthreads();
    }

    int g4 = g << 2;
    float* dst = doutf + OUT_Z + (size_t)mod * PM;
    #pragma unroll
    for (int mt = 0; mt < 4; mt++)
        #pragma unroll
        for (int nt = 0; nt < 4; nt++)
            #pragma unroll
            for (int reg = 0; reg < 4; reg++) {
                int row = by * 128 + wrow + mt * 16 + g4 + reg;
                int col = bx * 128 + wcol + nt * 16 + ml;
                dst[(size_t)row * 256 + col] = acc[mt][nt][reg];
            }
}

// ---------------- sem consistency scalar ----------------
__global__ __launch_bounds__(256) void sem_kernel(const float* __restrict__ cs,
                                                  float* __restrict__ doutf) {
    int t = threadIdx.x;
    float s = 0.f;
    #pragma unroll
    for (int b = 0; b < 16; b++)
        s += cs[b * 256 + t] * cs[4096 + b * 256 + t];
    #pragma unroll
    for (int mk = 1; mk < 64; mk <<= 1) s += __shfl_xor(s, mk);
    __shared__ float red[4];
    if ((t & 63) == 0) red[t >> 6] = s;
    __syncthreads();
    if (t == 0) {
        float tot = red[0] + red[1] + red[2] + red[3];
        float mv = tot / 16777216.0f;           // B*N*N
        mv = fminf(fmaxf(mv, 0.f), 1.f);
        doutf[OUT_SEM] = 1.0f - mv;
    }
}

extern "C" void kernel_launch(void* const* d_in, const int* in_sizes, int n_in,
                              void* d_out, int out_size, void* d_ws, size_t ws_size,
                              hipStream_t stream) {
    const float* f_rgb = (const float*)d_in[0];
    const float* f_sn  = (const float*)d_in[1];
    const float* p_rgb = (const float*)d_in[2];
    const float* p_sn  = (const float*)d_in[3];
    char* ws = (char*)d_ws;
    unsigned short* qb   = (unsigned short*)(ws + OFF_QB);
    unsigned short* pn   = (unsigned short*)(ws + OFF_PN);
    unsigned short* pnt  = (unsigned short*)(ws + OFF_PNT);
    float* u             = (float*)(ws + OFF_U);
    float* Tg            = (float*)(ws + OFF_T);
    float* Sc            = (float*)(ws + OFF_SC);
    float* cs            = (float*)(ws + OFF_CS);
    float* doutf         = (float*)d_out;

    proto_kernel<<<dim3(512), 64, 0, stream>>>(p_rgb, p_sn, pn, pnt, (float*)(ws + ZERO_OFF));
    gemm0_fused<<<dim3(2, 128, 2), 256, 0, stream>>>(f_rgb, f_sn, pn, qb, doutf, Tg);
    for (int p = 1; p <= 5; p++)
        pass_kernel<<<dim3(32, 16, 2), 256, 0, stream>>>(qb, u, Tg, Sc, p);
    gemm1_fused<<<dim3(2, 128, 2), 256, 0, stream>>>(qb, pnt, u, Sc, cs, doutf);
    sem_kernel<<<1, 256, 0, stream>>>(cs, doutf);
}